// Round 8
// baseline (194.704 us; speedup 1.0000x reference)
//
#include <hip/hip_runtime.h>
#include <cstddef>

#define LEN    1024
#define DIN    512
#define NHEAD  8
#define HDIM   64
#define BATCH  8

typedef __attribute__((ext_vector_type(8))) short  short8;
typedef __attribute__((ext_vector_type(4))) float  f32x4;

#define MFMA16(a, b, c) __builtin_amdgcn_mfma_f32_16x16x32_bf16((a), (b), (c), 0, 0, 0)
#define PERM_HI 0x07060302u
#define PERM_LO 0x05040100u

__device__ __forceinline__ unsigned short bf_hi(float x) {
    unsigned u = __float_as_uint(x);
    return (unsigned short)((u + 0x7fffu + ((u >> 16) & 1u)) >> 16);
}
__device__ __forceinline__ void bf_split(float x, unsigned short& h, unsigned short& l) {
    unsigned u  = __float_as_uint(x);
    unsigned hu = (u + 0x7fffu + ((u >> 16) & 1u)) >> 16;
    h = (unsigned short)hu;
    l = bf_hi(x - __uint_as_float(hu << 16));
}
__device__ __forceinline__ void unpack4(uint4 u, ushort4& h, ushort4& l) {
    h = make_ushort4((unsigned short)(u.x >> 16), (unsigned short)(u.y >> 16),
                     (unsigned short)(u.z >> 16), (unsigned short)(u.w >> 16));
    l = make_ushort4((unsigned short)(u.x & 0xffff), (unsigned short)(u.y & 0xffff),
                     (unsigned short)(u.z & 0xffff), (unsigned short)(u.w & 0xffff));
}
__device__ __forceinline__ void unpack8(uint4 a, uint4 b, uint4& h, uint4& l) {
    h = make_uint4(__builtin_amdgcn_perm(a.y, a.x, PERM_HI),
                   __builtin_amdgcn_perm(a.w, a.z, PERM_HI),
                   __builtin_amdgcn_perm(b.y, b.x, PERM_HI),
                   __builtin_amdgcn_perm(b.w, b.z, PERM_HI));
    l = make_uint4(__builtin_amdgcn_perm(a.y, a.x, PERM_LO),
                   __builtin_amdgcn_perm(a.w, a.z, PERM_LO),
                   __builtin_amdgcn_perm(b.y, b.x, PERM_LO),
                   __builtin_amdgcn_perm(b.w, b.z, PERM_LO));
}
__device__ __forceinline__ short8 as_s8(uint4 u) {
    union { uint4 u; short8 s; } x; x.u = u; return x.s;
}

// ---------------------------------------------------------------------------
// wprep: W[512k][512n] fp32 -> Wt hi/lo bf16 in [n][k] layout (B-frag layout).
// ---------------------------------------------------------------------------
__global__ __launch_bounds__(256)
void wprep(const float* __restrict__ WQ, const float* __restrict__ WK,
           const float* __restrict__ WV, unsigned short* __restrict__ wt)
{
    __shared__ float T[64][68];
    const int z = blockIdx.z;
    const float* W = (z == 0) ? WQ : (z == 1) ? WK : WV;
    unsigned short* Wth = wt + (size_t)z * 524288;
    unsigned short* Wtl = Wth + 262144;
    const int k0 = blockIdx.x * 64, n0 = blockIdx.y * 64;
    const int t = threadIdx.x;
    #pragma unroll
    for (int e = 0; e < 4; ++e) {
        int f = e * 256 + t, r = f >> 4, c4 = (f & 15) << 2;
        *(float4*)&T[r][c4] = *(const float4*)&W[(size_t)(k0 + r) * 512 + n0 + c4];
    }
    __syncthreads();
    #pragma unroll
    for (int e = 0; e < 4; ++e) {
        int f = e * 256 + t, nr = f >> 4, kc4 = (f & 15) << 2;
        ushort4 h, l;
        bf_split(T[kc4 + 0][nr], h.x, l.x);
        bf_split(T[kc4 + 1][nr], h.y, l.y);
        bf_split(T[kc4 + 2][nr], h.z, l.z);
        bf_split(T[kc4 + 3][nr], h.w, l.w);
        *(ushort4*)&Wth[(size_t)(n0 + nr) * 512 + k0 + kc4] = h;
        *(ushort4*)&Wtl[(size_t)(n0 + nr) * 512 + k0 + kc4] = l;
    }
}

// ---------------------------------------------------------------------------
// proj_mfma (unchanged from R7): split-bf16 MFMA, 128x128 tile, BK=32.
// ---------------------------------------------------------------------------
#define PSTR 40

__global__ __launch_bounds__(256, 3)
void proj_mfma(const float* __restrict__ Qin, const float* __restrict__ Kin,
               const float* __restrict__ Vin, const unsigned short* __restrict__ wt,
               unsigned int* __restrict__ qhl, unsigned int* __restrict__ khl,
               unsigned short* __restrict__ vh)
{
    __shared__ unsigned short Ah[128 * PSTR], Al[128 * PSTR],
                              Bh[128 * PSTR], Bl[128 * PSTR];
    const int z = blockIdx.z;
    const bool full = (z < 2);
    const float* X = (z == 0) ? Qin : (z == 1) ? Kin : Vin;
    const unsigned short* Wth = wt + (size_t)z * 524288;
    const unsigned short* Wtl = Wth + 262144;

    const int t = threadIdx.x, lane = t & 63, w = t >> 6;
    const int wm = w & 1, wn = w >> 1;
    const int m0 = blockIdx.x * 128, n0 = blockIdx.y * 128;
    const int lm = lane & 15, lq = lane >> 4;
    const int ar = t >> 1, ak = (t & 1) * 16;

    const float* Xp = X + (size_t)(m0 + ar) * 512 + ak;
    const unsigned short* Bph = Wth + (size_t)(n0 + ar) * 512 + ak;
    const unsigned short* Bpl = Wtl + (size_t)(n0 + ar) * 512 + ak;

    f32x4 acc[4][4];
    #pragma unroll
    for (int i = 0; i < 4; ++i)
        #pragma unroll
        for (int j = 0; j < 4; ++j) acc[i][j] = 0.f;

    float4 av[4];
    uint4 bh0, bh1, bl0, bl1;
    #pragma unroll
    for (int e = 0; e < 4; ++e) av[e] = *(const float4*)(Xp + e * 4);
    bh0 = *(const uint4*)(Bph);
    bh1 = *(const uint4*)(Bph + 8);
    if (full) { bl0 = *(const uint4*)(Bpl); bl1 = *(const uint4*)(Bpl + 8); }

    for (int k0 = 0; k0 < 512; k0 += 32) {
        __syncthreads();
        {
            const float* ff = (const float*)&av[0];
            uint hw[16];
            #pragma unroll
            for (int i = 0; i < 16; ++i) hw[i] = __float_as_uint(ff[i]) & 0xffff0000u;
            uint4 ahv  = make_uint4(__builtin_amdgcn_perm(hw[1],  hw[0],  PERM_HI),
                                    __builtin_amdgcn_perm(hw[3],  hw[2],  PERM_HI),
                                    __builtin_amdgcn_perm(hw[5],  hw[4],  PERM_HI),
                                    __builtin_amdgcn_perm(hw[7],  hw[6],  PERM_HI));
            uint4 ahv2 = make_uint4(__builtin_amdgcn_perm(hw[9],  hw[8],  PERM_HI),
                                    __builtin_amdgcn_perm(hw[11], hw[10], PERM_HI),
                                    __builtin_amdgcn_perm(hw[13], hw[12], PERM_HI),
                                    __builtin_amdgcn_perm(hw[15], hw[14], PERM_HI));
            *(uint4*)&Ah[ar * PSTR + ak]     = ahv;
            *(uint4*)&Ah[ar * PSTR + ak + 8] = ahv2;
            if (full) {
                uint lo[8];
                #pragma unroll
                for (int i = 0; i < 8; ++i) {
                    float r0 = ff[2*i]   - __uint_as_float(hw[2*i]);
                    float r1 = ff[2*i+1] - __uint_as_float(hw[2*i+1]);
                    lo[i] = ((uint)bf_hi(r1) << 16) | bf_hi(r0);
                }
                *(uint4*)&Al[ar * PSTR + ak]     = make_uint4(lo[0], lo[1], lo[2], lo[3]);
                *(uint4*)&Al[ar * PSTR + ak + 8] = make_uint4(lo[4], lo[5], lo[6], lo[7]);
            }
        }
        *(uint4*)&Bh[ar * PSTR + ak]     = bh0;
        *(uint4*)&Bh[ar * PSTR + ak + 8] = bh1;
        if (full) {
            *(uint4*)&Bl[ar * PSTR + ak]     = bl0;
            *(uint4*)&Bl[ar * PSTR + ak + 8] = bl1;
        }
        __syncthreads();

        if (k0 + 32 < 512) {
            #pragma unroll
            for (int e = 0; e < 4; ++e) av[e] = *(const float4*)(Xp + k0 + 32 + e * 4);
            bh0 = *(const uint4*)(Bph + k0 + 32);
            bh1 = *(const uint4*)(Bph + k0 + 40);
            if (full) {
                bl0 = *(const uint4*)(Bpl + k0 + 32);
                bl1 = *(const uint4*)(Bpl + k0 + 40);
            }
        }

        short8 a_h[4], a_l[4];
        #pragma unroll
        for (int mi = 0; mi < 4; ++mi) {
            int off = (wm * 64 + mi * 16 + lm) * PSTR + lq * 8;
            a_h[mi] = *(const short8*)&Ah[off];
            if (full) a_l[mi] = *(const short8*)&Al[off];
        }
        #pragma unroll
        for (int ni = 0; ni < 4; ++ni) {
            int off = (wn * 64 + ni * 16 + lm) * PSTR + lq * 8;
            short8 b_h = *(const short8*)&Bh[off];
            if (full) {
                short8 b_l = *(const short8*)&Bl[off];
                #pragma unroll
                for (int mi = 0; mi < 4; ++mi) {
                    acc[mi][ni] = MFMA16(a_l[mi], b_h, acc[mi][ni]);
                    acc[mi][ni] = MFMA16(a_h[mi], b_l, acc[mi][ni]);
                    acc[mi][ni] = MFMA16(a_h[mi], b_h, acc[mi][ni]);
                }
            } else {
                #pragma unroll
                for (int mi = 0; mi < 4; ++mi)
                    acc[mi][ni] = MFMA16(a_h[mi], b_h, acc[mi][ni]);
            }
        }
    }

    if (z < 2) {
        unsigned int* o = (z == 0) ? qhl : khl;
        const float sc = (z == 0) ? 0.18033688011112042f : 1.0f;  // 0.125*log2(e)
        #pragma unroll
        for (int mi = 0; mi < 4; ++mi)
            #pragma unroll
            for (int ni = 0; ni < 4; ++ni) {
                int n_abs = n0 + wn * 64 + ni * 16 + lm;
                int hd = n_abs >> 6, d = n_abs & 63;
                #pragma unroll
                for (int r = 0; r < 4; ++r) {
                    int m_abs = m0 + wm * 64 + mi * 16 + lq * 4 + r;
                    int b = m_abs >> 10, li = m_abs & 1023;
                    unsigned short hv, lv;
                    bf_split(acc[mi][ni][r] * sc, hv, lv);
                    o[(((size_t)b * NHEAD + hd) * LEN + li) * HDIM + d] =
                        ((unsigned)hv << 16) | lv;
                }
            }
    } else {
        #pragma unroll
        for (int mi = 0; mi < 4; ++mi) {
            int m_base = m0 + wm * 64 + mi * 16 + lq * 4;
            int b = m_base >> 10, l0 = m_base & 1023;
            #pragma unroll
            for (int ni = 0; ni < 4; ++ni) {
                int n_abs = n0 + wn * 64 + ni * 16 + lm;
                int hd = n_abs >> 6, d = n_abs & 63;
                ushort4 hv = make_ushort4(bf_hi(acc[mi][ni][0]), bf_hi(acc[mi][ni][1]),
                                          bf_hi(acc[mi][ni][2]), bf_hi(acc[mi][ni][3]));
                *(ushort4*)&vh[(((size_t)b * NHEAD + hd) * HDIM + d) * LEN + l0] = hv;
            }
        }
    }
}

// ---------------------------------------------------------------------------
// attn_mfma (R8): TRANSPOSED scores. Sc^T = MFMA(K_frag, Q_frag) puts q-rows
// on lm, keys on (lq,reg). Softmax: in-lane reduce + 2 shuffles. P packed as
// uints, xor-swizzled LDS (2-way free), read back as b128 B-frag for
// PV = MFMA(V_frag, P_frag) -> O^T; epilogue = 8 float4 stores. 2 barriers.
// ---------------------------------------------------------------------------
__global__ __launch_bounds__(256, 3)
void attn_mfma(const unsigned int* __restrict__ qhl, const unsigned int* __restrict__ khl,
               const unsigned short* __restrict__ vth, float* __restrict__ out)
{
    __shared__ unsigned short sm[23040];          // 46,080 B
    unsigned short* Kh = sm;                      // 64*72
    unsigned short* Kl = sm + 4608;               // 64*72
    unsigned short* Vt = sm + 9216;               // 64*72 [d][key]
    unsigned int*   Pb = (unsigned int*)(sm + 13824);  // [128 rows][36] uints
    unsigned short* Qsh = sm;                     // staging overlay
    unsigned short* Qsl = sm + 9216;

    const int t = threadIdx.x, lane = t & 63, w = t >> 6;
    const int lm = lane & 15, lq = lane >> 4;
    const int bx = blockIdx.x;
    const int idx = bx >> 1, par = bx & 1;
    const int bh = idx & 63;
    const int a  = idx >> 6;
    const int qt = par ? (7 - a) : a;
    const size_t base = (size_t)bh * LEN * HDIM;
    const unsigned int*   qb = qhl + base;
    const unsigned int*   kb = khl + base;
    const unsigned short* vb = vth + base;        // [d][l]
    const int Q0  = qt * 128;
    const int Q0w = Q0 + w * 32;

    // ---- stage Q (packed), pull split B-frags to registers ----
    #pragma unroll
    for (int e = 0; e < 8; ++e) {
        int f = e * 256 + t, r = f >> 4, c4 = (f & 15) << 2;
        uint4 u = *(const uint4*)&qb[(size_t)(Q0 + r) * 64 + c4];
        ushort4 h, l;
        unpack4(u, h, l);
        *(ushort4*)&Qsh[r * 72 + c4] = h;
        *(ushort4*)&Qsl[r * 72 + c4] = l;
    }
    __syncthreads();
    short8 qfh[2][2], qfl[2][2];
    #pragma unroll
    for (int mi = 0; mi < 2; ++mi)
        #pragma unroll
        for (int ks = 0; ks < 2; ++ks) {
            int off = (w * 32 + mi * 16 + lm) * 72 + ks * 32 + lq * 8;
            qfh[mi][ks] = *(const short8*)&Qsh[off];
            qfl[mi][ks] = *(const short8*)&Qsl[off];
        }

    float m_i[2], l_i[2];
    f32x4 oacc[2][4];
    #pragma unroll
    for (int mi = 0; mi < 2; ++mi) {
        m_i[mi] = -1e30f;
        l_i[mi] = 0.f;
        #pragma unroll
        for (int nd = 0; nd < 4; ++nd) oacc[mi][nd] = 0.f;
    }

    const int kr = t >> 2, kq = t & 3;            // K staging indices
    const int vd_ = t >> 3, vs8 = (t & 7) << 3;   // V staging indices

    uint4 kreg[4], vreg[2];
    #pragma unroll
    for (int e = 0; e < 4; ++e)
        kreg[e] = *(const uint4*)&kb[(size_t)kr * 64 + kq * 16 + e * 4];
    #pragma unroll
    for (int e = 0; e < 2; ++e)
        vreg[e] = *(const uint4*)&vb[(size_t)(e * 32 + vd_) * LEN + vs8];

    const int jend = 2 * qt + 1;
    for (int jb = 0; jb <= jend; ++jb) {
        __syncthreads();   // B1: prev iter's K/V reads (and Q staging) done
        {
            uint4 h0, l0, h1, l1;
            unpack8(kreg[0], kreg[1], h0, l0);
            unpack8(kreg[2], kreg[3], h1, l1);
            int ko = kr * 72 + kq * 16;
            *(uint4*)&Kh[ko]     = h0;
            *(uint4*)&Kh[ko + 8] = h1;
            *(uint4*)&Kl[ko]     = l0;
            *(uint4*)&Kl[ko + 8] = l1;
            *(uint4*)&Vt[(vd_)      * 72 + vs8] = vreg[0];
            *(uint4*)&Vt[(vd_ + 32) * 72 + vs8] = vreg[1];
        }
        __syncthreads();   // B2: staging visible

        if (jb < jend) {   // prefetch next tile; overlaps compute
            #pragma unroll
            for (int e = 0; e < 4; ++e)
                kreg[e] = *(const uint4*)&kb[(size_t)((jb + 1) * 64 + kr) * 64 + kq * 16 + e * 4];
            #pragma unroll
            for (int e = 0; e < 2; ++e)
                vreg[e] = *(const uint4*)&vb[(size_t)(e * 32 + vd_) * LEN + (jb + 1) * 64 + vs8];
        }

        const bool active = (jb * 64 <= Q0w + 31);
        if (active) {
            // ---- Sc^T = K * Q^T : rows=keys (lq*4+r), cols=q-rows (lm) ----
            f32x4 sf[2][4];
            #pragma unroll
            for (int mi = 0; mi < 2; ++mi)
                #pragma unroll
                for (int ni = 0; ni < 4; ++ni) sf[mi][ni] = 0.f;
            #pragma unroll
            for (int ks = 0; ks < 2; ++ks)
                #pragma unroll
                for (int ni = 0; ni < 4; ++ni) {
                    int off = (ni * 16 + lm) * 72 + ks * 32 + lq * 8;
                    short8 k_h = *(const short8*)&Kh[off];
                    short8 k_l = *(const short8*)&Kl[off];
                    #pragma unroll
                    for (int mi = 0; mi < 2; ++mi) {
                        sf[mi][ni] = MFMA16(k_h, qfl[mi][ks], sf[mi][ni]);
                        sf[mi][ni] = MFMA16(k_l, qfh[mi][ks], sf[mi][ni]);
                        sf[mi][ni] = MFMA16(k_h, qfh[mi][ks], sf[mi][ni]);
                    }
                }
            if (jb * 64 + 63 > Q0w) {   // causal mask near diagonal
                #pragma unroll
                for (int mi = 0; mi < 2; ++mi) {
                    int qi = Q0w + mi * 16 + lm;
                    #pragma unroll
                    for (int ni = 0; ni < 4; ++ni) {
                        int key0 = jb * 64 + ni * 16 + lq * 4;
                        #pragma unroll
                        for (int r = 0; r < 4; ++r)
                            if (key0 + r > qi) sf[mi][ni][r] = -1e30f;
                    }
                }
            }

            // ---- online softmax (base 2), rows on lm ----
            short8 pf[2][2];
            #pragma unroll
            for (int mi = 0; mi < 2; ++mi) {
                int rowl = w * 32 + mi * 16 + lm;
                unsigned X = (unsigned)(rowl & 3) << 3;
                unsigned int* prow = Pb + rowl * 36;

                f32x4 m4 = sf[mi][0];
                #pragma unroll
                for (int ni = 1; ni < 4; ++ni) {
                    m4[0] = fmaxf(m4[0], sf[mi][ni][0]);
                    m4[1] = fmaxf(m4[1], sf[mi][ni][1]);
                    m4[2] = fmaxf(m4[2], sf[mi][ni][2]);
                    m4[3] = fmaxf(m4[3], sf[mi][ni][3]);
                }
                float mv = fmaxf(fmaxf(m4[0], m4[1]), fmaxf(m4[2], m4[3]));
                mv = fmaxf(mv, __shfl_xor(mv, 16));
                mv = fmaxf(mv, __shfl_xor(mv, 32));
                float mo = m_i[mi];
                float mn = fmaxf(mo, mv);
                float al = __builtin_amdgcn_exp2f(mo - mn);
                m_i[mi] = mn;

                float rs = 0.f;
                #pragma unroll
                for (int ni = 0; ni < 4; ++ni) {
                    float p0 = __builtin_amdgcn_exp2f(sf[mi][ni][0] - mn);
                    float p1 = __builtin_amdgcn_exp2f(sf[mi][ni][1] - mn);
                    float p2 = __builtin_amdgcn_exp2f(sf[mi][ni][2] - mn);
                    float p3 = __builtin_amdgcn_exp2f(sf[mi][ni][3] - mn);
                    rs += (p0 + p1) + (p2 + p3);
                    unsigned col = 8u * ni + 2u * lq;
                    prow[(col ^ X)]     = ((uint)bf_hi(p1) << 16) | bf_hi(p0);
                    prow[(col ^ X) + 1] = ((uint)bf_hi(p3) << 16) | bf_hi(p2);
                }
                rs += __shfl_xor(rs, 16);
                rs += __shfl_xor(rs, 32);
                l_i[mi] = l_i[mi] * al + rs;
                #pragma unroll
                for (int nd = 0; nd < 4; ++nd) {
                    oacc[mi][nd][0] *= al;
                    oacc[mi][nd][1] *= al;
                    oacc[mi][nd][2] *= al;
                    oacc[mi][nd][3] *= al;
                }
                // read own row's P back as B-frag (same-wave round trip)
                #pragma unroll
                for (int ks = 0; ks < 2; ++ks) {
                    unsigned cb = ((unsigned)(16 * ks + 4 * lq)) ^ X;
                    uint4 pu = *(const uint4*)&prow[cb];
                    pf[mi][ks] = as_s8(pu);
                }
            }

            // ---- O^T += V^T * P^T ----
            #pragma unroll
            for (int ks = 0; ks < 2; ++ks)
                #pragma unroll
                for (int nd = 0; nd < 4; ++nd) {
                    short8 vf = *(const short8*)&Vt[(nd * 16 + lm) * 72 + ks * 32 + lq * 8];
                    #pragma unroll
                    for (int mi = 0; mi < 2; ++mi)
                        oacc[mi][nd] = MFMA16(vf, pf[mi][ks], oacc[mi][nd]);
                }
        }
    }

    // epilogue: O^T layout -> lane holds q-row (mi,lm), d = nd*16+lq*4+r
    const int b = bh >> 3, hd = bh & 7;
    #pragma unroll
    for (int mi = 0; mi < 2; ++mi) {
        int qrow = Q0w + mi * 16 + lm;
        float inv = 1.0f / l_i[mi];
        #pragma unroll
        for (int nd = 0; nd < 4; ++nd) {
            float4 o = make_float4(oacc[mi][nd][0] * inv, oacc[mi][nd][1] * inv,
                                   oacc[mi][nd][2] * inv, oacc[mi][nd][3] * inv);
            *(float4*)&out[((size_t)b * LEN + qrow) * (NHEAD * HDIM)
                           + hd * 64 + nd * 16 + lq * 4] = o;
        }
    }
}

// ---------------------------------------------------------------------------
extern "C" void kernel_launch(void* const* d_in, const int* in_sizes, int n_in,
                              void* d_out, int out_size, void* d_ws, size_t ws_size,
                              hipStream_t stream)
{
    const float* Qin = (const float*)d_in[0];
    const float* Kin = (const float*)d_in[1];
    const float* Vin = (const float*)d_in[2];
    const float* WQ  = (const float*)d_in[3];
    const float* WK  = (const float*)d_in[4];
    const float* WV  = (const float*)d_in[5];

    const size_t per = (size_t)BATCH * NHEAD * LEN * HDIM;   // 4,194,304 elements
    unsigned int*   qhl = (unsigned int*)d_ws;               // 16 MB
    unsigned int*   khl = qhl + per;                         // 16 MB
    unsigned short* vh  = (unsigned short*)(khl + per);      // 8 MB
    unsigned short* wt  = vh + per;                          // 3 MB   (total 43 MB)

    wprep    <<<dim3(8, 8, 3),  256, 0, stream>>>(WQ, WK, WV, wt);
    proj_mfma<<<dim3(64, 4, 3), 256, 0, stream>>>(Qin, Kin, Vin, wt, qhl, khl, vh);
    attn_mfma<<<dim3(512),      256, 0, stream>>>(qhl, khl, vh, (float*)d_out);
}